// Round 6
// baseline (4174.890 us; speedup 1.0000x reference)
//
#include <hip/hip_runtime.h>
#include <hip/hip_fp16.h>
#include <cstdint>
#include <cstddef>

#define N_E 2048
#define N_I 512
#define N_TOT 2560
#define BATCH 64
#define TSTEPS 512
#define INDIM 128
#define NQ 4                 // post-quadrants (blocks per batch)
#define QSZ 640              // N_TOT / NQ
#define NCOL (NQ * N_TOT)    // partitioned CSC columns
#define CAP (1u << 20)

// ------------------------------------------------------------------
// classify a flat index over the 4 weight matrices
// ------------------------------------------------------------------
__device__ __forceinline__ bool classify(long idx,
    const float* __restrict__ Wee, const float* __restrict__ Wie,
    const float* __restrict__ Wei, const float* __restrict__ Wii,
    float& w, int& col, int& post)
{
    const long EE = (long)N_E * N_E;
    const long IE = (long)N_I * N_E;
    const long EI = (long)N_E * N_I;
    float v; bool neg;
    if (idx < EE) {
        int r = (int)(idx >> 11), c = (int)(idx & (N_E - 1));
        v = Wee[idx]; post = r; col = c; neg = false;
    } else if (idx < EE + IE) {
        long j = idx - EE;
        int r = (int)(j >> 11), c = (int)(j & (N_E - 1));
        v = Wie[j]; post = N_E + r; col = c; neg = false;
    } else if (idx < EE + IE + EI) {
        long j = idx - EE - IE;
        int r = (int)(j >> 9), c = (int)(j & (N_I - 1));
        v = Wei[j]; post = r; col = N_E + c; neg = true;
    } else {
        long j = idx - EE - IE - EI;
        int r = (int)(j >> 9), c = (int)(j & (N_I - 1));
        v = Wii[j]; post = N_E + r; col = N_E + c; neg = true;
    }
    if (v <= 0.0f) return false;
    w = neg ? -v : v;
    return true;
}

__global__ void count_kernel(const float* __restrict__ Wee, const float* __restrict__ Wie,
                             const float* __restrict__ Wei, const float* __restrict__ Wii,
                             unsigned* __restrict__ cnt)
{
    const long total = (long)N_E * N_E + (long)N_I * N_E + (long)N_E * N_I + (long)N_I * N_I;
    long idx = (long)blockIdx.x * 256 + threadIdx.x;
    if (idx >= total) return;
    float w; int col, post;
    if (classify(idx, Wee, Wie, Wei, Wii, w, col, post)) {
        int q = post / QSZ;
        atomicAdd(&cnt[q * N_TOT + col], 1u);
    }
}

__global__ void scan_kernel(const unsigned* __restrict__ cnt,
                            unsigned* __restrict__ colinfo, unsigned* __restrict__ cursor)
{
    __shared__ unsigned sums[256];
    int t = threadIdx.x;
    int base = t * 40;                 // 10240 = 256 * 40
    unsigned loc[40];
    unsigned s = 0;
    for (int i = 0; i < 40; ++i) { loc[i] = s; s += cnt[base + i]; }
    sums[t] = s;
    __syncthreads();
    if (t == 0) {
        unsigned a = 0;
        for (int i = 0; i < 256; ++i) { unsigned v = sums[i]; sums[i] = a; a += v; }
    }
    __syncthreads();
    unsigned offt = sums[t];
    for (int i = 0; i < 40; ++i) {
        unsigned beg = offt + loc[i];
        if (beg > CAP) beg = CAP;
        unsigned len = cnt[base + i];
        if (len > 1023u) len = 1023u;
        colinfo[base + i] = (beg << 10) | len;
        cursor[base + i] = beg;
    }
}

__global__ void fill_kernel(const float* __restrict__ Wee, const float* __restrict__ Wie,
                            const float* __restrict__ Wei, const float* __restrict__ Wii,
                            unsigned* __restrict__ cursor, unsigned* __restrict__ nzd)
{
    const long total = (long)N_E * N_E + (long)N_I * N_E + (long)N_E * N_I + (long)N_I * N_I;
    long idx = (long)blockIdx.x * 256 + threadIdx.x;
    if (idx >= total) return;
    float w; int col, post;
    if (classify(idx, Wee, Wie, Wei, Wii, w, col, post)) {
        int q = post / QSZ;
        int local = post - q * QSZ;      // 0..639
        unsigned pos = atomicAdd(&cursor[q * N_TOT + col], 1u);
        if (pos < CAP) {
            unsigned short h = __half_as_ushort(__float2half(w));
            nzd[pos] = ((unsigned)h << 16) | (unsigned)local;
        }
    }
}

// ------------------------------------------------------------------
// Input projection GEMM (unchanged)
// ------------------------------------------------------------------
#define PBM 128
#define PBN 64
#define PBK 32
__global__ __launch_bounds__(256) void proj_kernel(
    const float* __restrict__ x, const float* __restrict__ We, const float* __restrict__ Wi,
    float* __restrict__ out, int t0)
{
    __shared__ __align__(16) float As[PBK][132];
    __shared__ __align__(16) float Bs[PBK][68];
    int tid = threadIdx.x;
    int bx = blockIdx.x, by = blockIdx.y;
    int tx = tid & 15, ty = tid >> 4;
    float acc[8][4];
#pragma unroll
    for (int i = 0; i < 8; ++i)
#pragma unroll
        for (int j = 0; j < 4; ++j) acc[i][j] = 0.0f;

    for (int kb = 0; kb < INDIM; kb += PBK) {
#pragma unroll
        for (int it = 0; it < 4; ++it) {
            int idx = it * 256 + tid;
            int kq = idx & 7, ml = idx >> 3;
            int m = by * PBM + ml;
            int b = m & 63, tl = m >> 6;
            const float* arow = x + ((size_t)b * TSTEPS + (size_t)(t0 + tl)) * INDIM;
            float4 v = *(const float4*)(arow + kb + kq * 4);
            As[kq * 4 + 0][ml] = v.x; As[kq * 4 + 1][ml] = v.y;
            As[kq * 4 + 2][ml] = v.z; As[kq * 4 + 3][ml] = v.w;
        }
#pragma unroll
        for (int it = 0; it < 2; ++it) {
            int idx = it * 256 + tid;
            int kq = idx & 7, nl = idx >> 3;
            int n = bx * PBN + nl;
            const float* brow = (n < N_E) ? (We + (size_t)n * INDIM)
                                          : (Wi + (size_t)(n - N_E) * INDIM);
            float4 v = *(const float4*)(brow + kb + kq * 4);
            Bs[kq * 4 + 0][nl] = v.x; Bs[kq * 4 + 1][nl] = v.y;
            Bs[kq * 4 + 2][nl] = v.z; Bs[kq * 4 + 3][nl] = v.w;
        }
        __syncthreads();
#pragma unroll
        for (int k = 0; k < PBK; ++k) {
            float4 a0 = *(const float4*)&As[k][ty * 8];
            float4 a1 = *(const float4*)&As[k][ty * 8 + 4];
            float4 b0 = *(const float4*)&Bs[k][tx * 4];
            float a[8] = {a0.x, a0.y, a0.z, a0.w, a1.x, a1.y, a1.z, a1.w};
            float bb[4] = {b0.x, b0.y, b0.z, b0.w};
#pragma unroll
            for (int i = 0; i < 8; ++i)
#pragma unroll
                for (int j = 0; j < 4; ++j)
                    acc[i][j] = fmaf(a[i], bb[j], acc[i][j]);
        }
        __syncthreads();
    }
#pragma unroll
    for (int i = 0; i < 8; ++i) {
        int m = by * PBM + ty * 8 + i;
        float4 o = make_float4(acc[i][0], acc[i][1], acc[i][2], acc[i][3]);
        *(float4*)(out + (size_t)m * N_TOT + bx * PBN + tx * 4) = o;
    }
}

__device__ __forceinline__ float inline_proj(const float* __restrict__ x,
                                             const float* __restrict__ We_in,
                                             const float* __restrict__ Wi_in,
                                             int b, int t, int n)
{
    const float* xr = x + ((size_t)b * TSTEPS + (size_t)t) * INDIM;
    const float* wr = (n < N_E) ? (We_in + (size_t)n * INDIM)
                                : (Wi_in + (size_t)(n - N_E) * INDIM);
    float a = 0.f;
#pragma unroll
    for (int k = 0; k < INDIM; k += 4) {
        float4 w = *(const float4*)(wr + k);
        float4 xv = *(const float4*)(xr + k);
        a = fmaf(w.x, xv.x, a); a = fmaf(w.y, xv.y, a);
        a = fmaf(w.z, xv.z, a); a = fmaf(w.w, xv.w, a);
    }
    return a;
}

// ------------------------------------------------------------------
// 4-blocks-per-batch LIF sim. Block bid: b = bid&63, q = bid>>6.
// Each block owns posts [q*640, (q+1)*640): private I_acc/LIF/state.
// Per step: poll sibling flags -> read spike bitmap(t-1) -> expand to
// <=32-entry segments -> scatter via own-quadrant CSC (LDS atomics,
// 1/4 the ops) -> LIF -> write own bitmap segment + flag.
// ------------------------------------------------------------------
__global__ __launch_bounds__(1024) void sim_kernel(
    const float* __restrict__ i_inp,
    const float* __restrict__ x, const float* __restrict__ We_in, const float* __restrict__ Wi_in,
    const unsigned* __restrict__ colinfo, const unsigned* __restrict__ nzd,
    float* __restrict__ gv, float* __restrict__ gi, unsigned* __restrict__ g_cnt,
    unsigned long long* __restrict__ g_bm,   // [2][BATCH][40]
    unsigned* __restrict__ g_flag,           // [BATCH][NQ]
    int t0, int tc, int first)
{
    __shared__ float v_s[QSZ], i_s[QSZ], I_acc[QSZ];
    __shared__ unsigned cnt_s[QSZ];
    __shared__ unsigned ci_lds[N_TOT];
    __shared__ unsigned list_s[N_TOT];       // entry: pre_j | (part<<12)
    __shared__ unsigned nent_s;
    __shared__ unsigned long long bm_lds[40];

    int bid = blockIdx.x;
    int b = bid & 63, q = bid >> 6;
    int tid = threadIdx.x, lane = tid & 63, wid = tid >> 6;
    int hseg = lane >> 5, hl = lane & 31;    // two 32-lane halves per wave

    for (int j = tid; j < N_TOT; j += 1024) ci_lds[j] = colinfo[q * N_TOT + j];
    size_t sbase = (size_t)(q * BATCH + b) * QSZ;
    if (first) {
        for (int l = tid; l < QSZ; l += 1024) { v_s[l] = 0.f; i_s[l] = 0.f; cnt_s[l] = 0u; }
    } else {
        for (int l = tid; l < QSZ; l += 1024) {
            v_s[l] = gv[sbase + l]; i_s[l] = gi[sbase + l]; cnt_s[l] = g_cnt[sbase + l];
        }
    }
    __syncthreads();

    for (int tl = 0; tl < tc; ++tl) {
        int tg = t0 + tl;

        // ---- A0: wave0 polls siblings + fetches bitmap; other waves load input ----
        if (wid == 0) {
            if (tg == 0) {
                if (lane < 40) bm_lds[lane] = 0ull;
            } else {
                if (lane < NQ) {
                    int guard = 0;
                    while (__hip_atomic_load(&g_flag[b * NQ + lane], __ATOMIC_ACQUIRE,
                                             __HIP_MEMORY_SCOPE_AGENT) < (unsigned)tg) {
                        if (++guard > (1 << 20)) break;   // failsafe: never hang
                    }
                }
                const unsigned long long* src = g_bm + ((size_t)((tg - 1) & 1) * BATCH + b) * 40;
                if (lane < 40)
                    bm_lds[lane] = __hip_atomic_load(&src[lane], __ATOMIC_RELAXED,
                                                     __HIP_MEMORY_SCOPE_AGENT);
            }
            if (lane == 63) nent_s = 0u;
        } else {
            int l = tid - 64;
            if (l < QSZ) {
                if (i_inp)
                    I_acc[l] = i_inp[((size_t)tl * BATCH + b) * N_TOT + q * QSZ + l];
                else
                    I_acc[l] = inline_proj(x, We_in, Wi_in, b, tg, q * QSZ + l);
            }
        }
        __syncthreads();

        // ---- A1: expand bitmap -> <=32-entry segment list ----
        if (tg > 0) {
            for (int j0 = tid; j0 < N_TOT; j0 += 1024) {
                unsigned long long wv = bm_lds[j0 >> 6];
                bool sp = (wv >> (j0 & 63)) & 1ull;
                unsigned len = sp ? (ci_lds[j0] & 1023u) : 0u;
                unsigned k = (len + 31u) >> 5;
                if (__ballot(k != 0)) {
                    unsigned pre = k;
#pragma unroll
                    for (int d = 1; d < 64; d <<= 1) {
                        unsigned t2 = __shfl_up(pre, d);
                        if (lane >= d) pre += t2;
                    }
                    unsigned excl = pre - k;
                    unsigned tot = __shfl(pre, 63);
                    unsigned basew = 0;
                    if (lane == 0 && tot) basew = atomicAdd(&nent_s, tot);
                    basew = __shfl(basew, 0);
                    for (unsigned c = 0; c < k; ++c)
                        list_s[basew + excl + c] = (unsigned)j0 | (c << 12);
                }
            }
        }
        __syncthreads();

        // ---- A2: scatter (2 segments per wave-instr, 4 deep in flight) ----
        {
            int nent = (int)nent_s;
            for (int g0 = wid * 8; g0 < nent; g0 += 128) {
                unsigned rem[4], eV[4];
#pragma unroll
                for (int d = 0; d < 4; ++d) {
                    int s = g0 + 2 * d + hseg;
                    unsigned r = 0, beg = 0;
                    if (s < nent) {
                        unsigned e = list_s[s];
                        unsigned ci = ci_lds[e & 4095u];
                        unsigned part = e >> 12;
                        unsigned len = ci & 1023u;
                        beg = (ci >> 10) + part * 32u;
                        unsigned rr = len - part * 32u;
                        r = rr > 32u ? 32u : rr;
                    }
                    rem[d] = r;
                    eV[d] = ((unsigned)hl < r) ? nzd[beg + hl] : 0u;
                }
#pragma unroll
                for (int d = 0; d < 4; ++d)
                    if ((unsigned)hl < rem[d])
                        atomicAdd(&I_acc[eV[d] & 0xFFFFu],
                                  __half2float(__ushort_as_half((unsigned short)(eV[d] >> 16))));
            }
        }
        __syncthreads();

        // ---- B: LIF + own bitmap segment ----
        if (tid < QSZ) {
            int l = tid, ng = q * QSZ + l;
            float I = I_acc[l];
            float v = v_s[l], ii = i_s[l];
            float tm = (ng < N_E) ? 0.05f : 0.1f;
            float vd = v + tm * ((0.0f - v) + ii);
            bool z = vd > 1.0f;
            v_s[l] = z ? 0.0f : vd;
            i_s[l] = 0.8f * ii + I;
            if (z && ng < N_E) cnt_s[l]++;
            unsigned long long msk = __ballot(z);
            if (lane == 0) bm_lds[wid] = msk;   // waves 0..9
        }
        __syncthreads();

        if (wid == 0) {
            unsigned long long* dst = g_bm + ((size_t)(tg & 1) * BATCH + b) * 40 + q * 10;
            if (lane < 10)
                __hip_atomic_store(&dst[lane], bm_lds[lane], __ATOMIC_RELAXED,
                                   __HIP_MEMORY_SCOPE_AGENT);
            if (lane == 0)
                __hip_atomic_store(&g_flag[b * NQ + q], (unsigned)(tg + 1), __ATOMIC_RELEASE,
                                   __HIP_MEMORY_SCOPE_AGENT);
        }
        // no barrier needed: wave0 is both flag-writer and next-step poller;
        // I_acc rewrite next step is fenced by the barrier above.
    }

    for (int l = tid; l < QSZ; l += 1024) {
        gv[sbase + l] = v_s[l];
        gi[sbase + l] = i_s[l];
        g_cnt[sbase + l] = cnt_s[l];
    }
}

// ------------------------------------------------------------------
// Readout over quadrant-partitioned counts
// ------------------------------------------------------------------
__global__ __launch_bounds__(256) void readout_kernel(
    const unsigned* __restrict__ g_cnt,
    const float* __restrict__ rw, const float* __restrict__ rb, float* __restrict__ out)
{
    int b = blockIdx.x, tid = threadIdx.x;
    float a0 = 0.f, a1 = 0.f, a2 = 0.f;
    for (int n = tid; n < N_E; n += 256) {
        int q = n / QSZ, l = n - q * QSZ;
        float c = (float)g_cnt[(size_t)(q * BATCH + b) * QSZ + l];
        a0 = fmaf(c, rw[n], a0);
        a1 = fmaf(c, rw[N_E + n], a1);
        a2 = fmaf(c, rw[2 * N_E + n], a2);
    }
#pragma unroll
    for (int off = 32; off > 0; off >>= 1) {
        a0 += __shfl_down(a0, off);
        a1 += __shfl_down(a1, off);
        a2 += __shfl_down(a2, off);
    }
    __shared__ float part[3][4];
    int wid = tid >> 6, lane = tid & 63;
    if (lane == 0) { part[0][wid] = a0; part[1][wid] = a1; part[2][wid] = a2; }
    __syncthreads();
    if (tid == 0) {
        float s0 = part[0][0] + part[0][1] + part[0][2] + part[0][3];
        float s1 = part[1][0] + part[1][1] + part[1][2] + part[1][3];
        float s2 = part[2][0] + part[2][1] + part[2][2] + part[2][3];
        const float inv = 1.0f / 512.0f;
        out[b * 3 + 0] = fmaf(s0, inv, rb[0]);
        out[b * 3 + 1] = fmaf(s1, inv, rb[1]);
        out[b * 3 + 2] = fmaf(s2, inv, rb[2]);
    }
}

// ------------------------------------------------------------------
extern "C" void kernel_launch(void* const* d_in, const int* in_sizes, int n_in,
                              void* d_out, int out_size, void* d_ws, size_t ws_size,
                              hipStream_t stream)
{
    const float* x     = (const float*)d_in[0];
    const float* Wee   = (const float*)d_in[1];
    const float* Wie   = (const float*)d_in[2];
    const float* Wei   = (const float*)d_in[3];
    const float* Wii   = (const float*)d_in[4];
    const float* We_in = (const float*)d_in[5];
    const float* Wi_in = (const float*)d_in[6];
    const float* rw    = (const float*)d_in[7];
    const float* rb    = (const float*)d_in[8];
    float* out = (float*)d_out;
    char* ws = (char*)d_ws;

    size_t off = 0;
    auto alloc = [&](size_t bytes) {
        size_t o = off;
        off = (off + bytes + 255) & ~(size_t)255;
        return o;
    };
    size_t o_cnt     = alloc((size_t)NCOL * 4);
    size_t o_colinfo = alloc((size_t)NCOL * 4);
    size_t o_cursor  = alloc((size_t)NCOL * 4);
    size_t o_nzd     = alloc((size_t)CAP * 4);
    size_t o_gv      = alloc((size_t)NQ * BATCH * QSZ * 4);
    size_t o_gi      = alloc((size_t)NQ * BATCH * QSZ * 4);
    size_t o_gcnt    = alloc((size_t)NQ * BATCH * QSZ * 4);
    size_t o_gbm     = alloc((size_t)2 * BATCH * 40 * 8);
    size_t o_gflag   = alloc((size_t)BATCH * NQ * 4);
    size_t o_iinp    = off;

    int tc = 0;
    if (ws_size > o_iinp) {
        size_t avail = ws_size - o_iinp;
        tc = TSTEPS;
        while (tc >= 2 && (size_t)tc * BATCH * N_TOT * 4 > avail) tc >>= 1;
        if (tc < 2) tc = 0;
    }

    unsigned*           p_cnt     = (unsigned*)(ws + o_cnt);
    unsigned*           p_colinfo = (unsigned*)(ws + o_colinfo);
    unsigned*           p_cursor  = (unsigned*)(ws + o_cursor);
    unsigned*           p_nzd     = (unsigned*)(ws + o_nzd);
    float*              p_gv      = (float*)(ws + o_gv);
    float*              p_gi      = (float*)(ws + o_gi);
    unsigned*           p_gcnt    = (unsigned*)(ws + o_gcnt);
    unsigned long long* p_gbm     = (unsigned long long*)(ws + o_gbm);
    unsigned*           p_gflag   = (unsigned*)(ws + o_gflag);
    float*              p_iinp    = (float*)(ws + o_iinp);

    // ---- build partitioned CSC ----
    hipMemsetAsync(ws + o_cnt, 0, (size_t)NCOL * 4, stream);
    hipMemsetAsync(ws + o_gflag, 0, (size_t)BATCH * NQ * 4, stream);
    const long total = (long)N_E * N_E + (long)N_I * N_E + (long)N_E * N_I + (long)N_I * N_I;
    int nblk = (int)((total + 255) / 256);
    count_kernel<<<nblk, 256, 0, stream>>>(Wee, Wie, Wei, Wii, p_cnt);
    scan_kernel<<<1, 256, 0, stream>>>(p_cnt, p_colinfo, p_cursor);
    fill_kernel<<<nblk, 256, 0, stream>>>(Wee, Wie, Wei, Wii, p_cursor, p_nzd);

    // ---- time loop ----
    if (tc >= 2) {
        for (int t0 = 0; t0 < TSTEPS; t0 += tc) {
            dim3 pg(N_TOT / PBN, (tc * BATCH) / PBM);
            proj_kernel<<<pg, 256, 0, stream>>>(x, We_in, Wi_in, p_iinp, t0);
            sim_kernel<<<NQ * BATCH, 1024, 0, stream>>>(
                p_iinp, x, We_in, Wi_in, p_colinfo, p_nzd,
                p_gv, p_gi, p_gcnt, p_gbm, p_gflag,
                t0, tc, (t0 == 0) ? 1 : 0);
        }
    } else {
        sim_kernel<<<NQ * BATCH, 1024, 0, stream>>>(
            nullptr, x, We_in, Wi_in, p_colinfo, p_nzd,
            p_gv, p_gi, p_gcnt, p_gbm, p_gflag,
            0, TSTEPS, 1);
    }

    // ---- readout ----
    readout_kernel<<<BATCH, 256, 0, stream>>>(p_gcnt, rw, rb, out);
}

// Round 7
// 3651.339 us; speedup vs baseline: 1.1434x; 1.1434x over previous
//
#include <hip/hip_runtime.h>
#include <hip/hip_fp16.h>
#include <cstdint>
#include <cstddef>

#define N_E 2048
#define N_I 512
#define N_TOT 2560
#define BATCH 64
#define TSTEPS 512
#define INDIM 128
#define CAP (1u << 20)   // nz capacity (expected ~330K)

// ------------------------------------------------------------------
// CSC build: counts -> scan -> fill.
//   col 0..2047   : E presynaptic j  (Wee -> post 0..2047 (+), Wie -> 2048+r (+))
//   col 2048..2559: I presynaptic j  (Wei -> post 0..2047 (-), Wii -> 2048+r (-))
// Synapse packed u32: (f16_bits(w) << 16) | post_index   (4 B/synapse)
// colinfo packed u32: (col_begin << 10) | col_len
// ------------------------------------------------------------------
__global__ void count_kernel(const float* __restrict__ Wee, const float* __restrict__ Wie,
                             const float* __restrict__ Wei, const float* __restrict__ Wii,
                             unsigned* __restrict__ cnt)
{
    const long EE = (long)N_E * N_E;
    const long IE = (long)N_I * N_E;
    const long EI = (long)N_E * N_I;
    const long II = (long)N_I * N_I;
    long idx = (long)blockIdx.x * 256 + threadIdx.x;
    long total = EE + IE + EI + II;
    if (idx >= total) return;
    float v; int col;
    if (idx < EE) {
        v = Wee[idx]; col = (int)(idx & (N_E - 1));
    } else if (idx < EE + IE) {
        long j = idx - EE; v = Wie[j]; col = (int)(j & (N_E - 1));
    } else if (idx < EE + IE + EI) {
        long j = idx - EE - IE; v = Wei[j]; col = N_E + (int)(j & (N_I - 1));
    } else {
        long j = idx - EE - IE - EI; v = Wii[j]; col = N_E + (int)(j & (N_I - 1));
    }
    if (v > 0.0f) atomicAdd(&cnt[col], 1u);
}

__global__ void scan_kernel(const unsigned* __restrict__ cnt,
                            unsigned* __restrict__ colinfo, unsigned* __restrict__ cursor)
{
    __shared__ unsigned sums[256];
    int t = threadIdx.x;
    int base = t * 10;                 // 2560 = 256 * 10
    unsigned loc[10];
    unsigned s = 0;
    for (int i = 0; i < 10; ++i) { loc[i] = s; s += cnt[base + i]; }
    sums[t] = s;
    __syncthreads();
    if (t == 0) {
        unsigned a = 0;
        for (int i = 0; i < 256; ++i) { unsigned v = sums[i]; sums[i] = a; a += v; }
    }
    __syncthreads();
    unsigned offt = sums[t];
    for (int i = 0; i < 10; ++i) {
        unsigned beg = offt + loc[i];
        if (beg > CAP) beg = CAP;
        unsigned len = cnt[base + i];
        if (len > 1023u) len = 1023u;
        colinfo[base + i] = (beg << 10) | len;
        cursor[base + i] = beg;
    }
}

__global__ void fill_kernel(const float* __restrict__ Wee, const float* __restrict__ Wie,
                            const float* __restrict__ Wei, const float* __restrict__ Wii,
                            unsigned* __restrict__ cursor,
                            unsigned* __restrict__ nzd)
{
    const long EE = (long)N_E * N_E;
    const long IE = (long)N_I * N_E;
    const long EI = (long)N_E * N_I;
    const long II = (long)N_I * N_I;
    long idx = (long)blockIdx.x * 256 + threadIdx.x;
    long total = EE + IE + EI + II;
    if (idx >= total) return;
    float v; int col; int post; bool neg;
    if (idx < EE) {
        int r = (int)(idx >> 11), c = (int)(idx & (N_E - 1));
        v = Wee[idx]; post = r; col = c; neg = false;
    } else if (idx < EE + IE) {
        long j = idx - EE;
        int r = (int)(j >> 11), c = (int)(j & (N_E - 1));
        v = Wie[j]; post = N_E + r; col = c; neg = false;
    } else if (idx < EE + IE + EI) {
        long j = idx - EE - IE;
        int r = (int)(j >> 9), c = (int)(j & (N_I - 1));
        v = Wei[j]; post = r; col = N_E + c; neg = true;
    } else {
        long j = idx - EE - IE - EI;
        int r = (int)(j >> 9), c = (int)(j & (N_I - 1));
        v = Wii[j]; post = N_E + r; col = N_E + c; neg = true;
    }
    if (v > 0.0f) {
        unsigned pos = atomicAdd(&cursor[col], 1u);
        if (pos < CAP) {
            float w = neg ? -v : v;
            unsigned short h = __half_as_ushort(__float2half(w));
            nzd[pos] = ((unsigned)h << 16) | (unsigned)post;
        }
    }
}

// ------------------------------------------------------------------
// Input projection GEMM: out[(tl*64+b)*2560 + n] = dot(x[b, t0+tl, :], W[n, :])
// ------------------------------------------------------------------
#define PBM 128
#define PBN 64
#define PBK 32
__global__ __launch_bounds__(256) void proj_kernel(
    const float* __restrict__ x, const float* __restrict__ We, const float* __restrict__ Wi,
    float* __restrict__ out, int t0)
{
    __shared__ __align__(16) float As[PBK][132];
    __shared__ __align__(16) float Bs[PBK][68];
    int tid = threadIdx.x;
    int bx = blockIdx.x, by = blockIdx.y;
    int tx = tid & 15, ty = tid >> 4;
    float acc[8][4];
#pragma unroll
    for (int i = 0; i < 8; ++i)
#pragma unroll
        for (int j = 0; j < 4; ++j) acc[i][j] = 0.0f;

    for (int kb = 0; kb < INDIM; kb += PBK) {
#pragma unroll
        for (int it = 0; it < 4; ++it) {
            int idx = it * 256 + tid;
            int kq = idx & 7, ml = idx >> 3;
            int m = by * PBM + ml;
            int b = m & 63, tl = m >> 6;
            const float* arow = x + ((size_t)b * TSTEPS + (size_t)(t0 + tl)) * INDIM;
            float4 v = *(const float4*)(arow + kb + kq * 4);
            As[kq * 4 + 0][ml] = v.x; As[kq * 4 + 1][ml] = v.y;
            As[kq * 4 + 2][ml] = v.z; As[kq * 4 + 3][ml] = v.w;
        }
#pragma unroll
        for (int it = 0; it < 2; ++it) {
            int idx = it * 256 + tid;
            int kq = idx & 7, nl = idx >> 3;
            int n = bx * PBN + nl;
            const float* brow = (n < N_E) ? (We + (size_t)n * INDIM)
                                          : (Wi + (size_t)(n - N_E) * INDIM);
            float4 v = *(const float4*)(brow + kb + kq * 4);
            Bs[kq * 4 + 0][nl] = v.x; Bs[kq * 4 + 1][nl] = v.y;
            Bs[kq * 4 + 2][nl] = v.z; Bs[kq * 4 + 3][nl] = v.w;
        }
        __syncthreads();
#pragma unroll
        for (int k = 0; k < PBK; ++k) {
            float4 a0 = *(const float4*)&As[k][ty * 8];
            float4 a1 = *(const float4*)&As[k][ty * 8 + 4];
            float4 b0 = *(const float4*)&Bs[k][tx * 4];
            float a[8] = {a0.x, a0.y, a0.z, a0.w, a1.x, a1.y, a1.z, a1.w};
            float bb[4] = {b0.x, b0.y, b0.z, b0.w};
#pragma unroll
            for (int i = 0; i < 8; ++i)
#pragma unroll
                for (int j = 0; j < 4; ++j)
                    acc[i][j] = fmaf(a[i], bb[j], acc[i][j]);
        }
        __syncthreads();
    }
#pragma unroll
    for (int i = 0; i < 8; ++i) {
        int m = by * PBM + ty * 8 + i;
        float4 o = make_float4(acc[i][0], acc[i][1], acc[i][2], acc[i][3]);
        *(float4*)(out + (size_t)m * N_TOT + bx * PBN + tx * 4) = o;
    }
}

// ------------------------------------------------------------------
// on-the-fly input projection (fallback path only)
// ------------------------------------------------------------------
__device__ __forceinline__ float inline_proj(const float* __restrict__ x,
                                             const float* __restrict__ We_in,
                                             const float* __restrict__ Wi_in,
                                             int b, int t, int n)
{
    const float* xr = x + ((size_t)b * TSTEPS + (size_t)t) * INDIM;
    const float* wr = (n < N_E) ? (We_in + (size_t)n * INDIM)
                                : (Wi_in + (size_t)(n - N_E) * INDIM);
    float a = 0.f;
#pragma unroll
    for (int k = 0; k < INDIM; k += 4) {
        float4 w = *(const float4*)(wr + k);
        float4 xv = *(const float4*)(xr + k);
        a = fmaf(w.x, xv.x, a);
        a = fmaf(w.y, xv.y, a);
        a = fmaf(w.z, xv.z, a);
        a = fmaf(w.w, xv.w, a);
    }
    return a;
}

// ------------------------------------------------------------------
// Persistent per-batch LIF sim (r5 structure; latency-batched scatter).
// One block per batch; double-buffered I_acc/spike list; 2 barriers/step.
// Scatter: 4 spikes x 3 fixed 64-wide slots per burst, clamped
// unconditional loads (12 independent global_load_dword in flight),
// predicated LDS atomics. colinfo cached in LDS (no global colptr hop).
// ------------------------------------------------------------------
#define SG 4   // spikes per burst per wave
__global__ __launch_bounds__(1024) void sim_kernel(
    const float* __restrict__ i_inp,   // precomputed input currents; may be null
    const float* __restrict__ x, const float* __restrict__ We_in, const float* __restrict__ Wi_in,
    const unsigned* __restrict__ colinfo, const unsigned* __restrict__ nzd,
    float* __restrict__ gv_e, float* __restrict__ gi_e,
    float* __restrict__ gv_i, float* __restrict__ gi_i,
    unsigned* __restrict__ g_cnt, int* __restrict__ g_list, int* __restrict__ g_nspk,
    int t0, int tc, int first)
{
    __shared__ float v_e[N_E], i_e[N_E];
    __shared__ float v_i[N_I], i_i[N_I];
    __shared__ float I_acc[2][N_TOT];
    __shared__ unsigned cnt[N_E];
    __shared__ unsigned ci_lds[N_TOT];
    __shared__ int list_s[2][N_TOT];
    __shared__ int nspk_s[2];

    int b = blockIdx.x, tid = threadIdx.x;
    int lane = tid & 63, wid = tid >> 6;

    for (int n = tid; n < N_TOT; n += 1024) ci_lds[n] = colinfo[n];

    if (first) {
        for (int n = tid; n < N_E; n += 1024) { v_e[n] = 0.f; i_e[n] = 0.f; cnt[n] = 0u; }
        for (int n = tid; n < N_I; n += 1024) { v_i[n] = 0.f; i_i[n] = 0.f; }
        if (tid == 0) nspk_s[0] = 0;
    } else {
        for (int n = tid; n < N_E; n += 1024) {
            v_e[n] = gv_e[(size_t)b * N_E + n];
            i_e[n] = gi_e[(size_t)b * N_E + n];
            cnt[n] = g_cnt[(size_t)b * N_E + n];
        }
        for (int n = tid; n < N_I; n += 1024) {
            v_i[n] = gv_i[(size_t)b * N_I + n];
            i_i[n] = gi_i[(size_t)b * N_I + n];
        }
        if (tid == 0) nspk_s[0] = g_nspk[b];
        __syncthreads();
        for (int s = tid; s < nspk_s[0]; s += 1024) list_s[0][s] = g_list[(size_t)b * N_TOT + s];
    }
    // init I_acc[0] with input row for first step of this chunk
    if (i_inp) {
        const float* src = i_inp + (size_t)b * N_TOT;    // tl = 0
        for (int n = tid; n < N_TOT; n += 1024) I_acc[0][n] = src[n];
    } else {
        for (int n = tid; n < N_TOT; n += 1024)
            I_acc[0][n] = inline_proj(x, We_in, Wi_in, b, t0, n);
    }
    __syncthreads();

    for (int tl = 0; tl < tc; ++tl) {
        int cur = tl & 1, nxt = cur ^ 1;

        // ---- phase A: prefetch next input row; batched scatter ----
        float pf0 = 0.f, pf1 = 0.f, pf2 = 0.f;
        bool havepf = (i_inp != nullptr) && (tl + 1 < tc);
        if (havepf) {
            const float* src = i_inp + ((size_t)(tl + 1) * BATCH + b) * N_TOT;
            pf0 = src[tid];
            pf1 = src[tid + 1024];
            if (tid < N_TOT - 2048) pf2 = src[tid + 2048];
        }
        if (tid == 0) nspk_s[nxt] = 0;

        int ns = nspk_s[cur];
        for (int s0 = wid * SG; s0 < ns; s0 += 16 * SG) {
            unsigned beg[SG]; int len[SG];
#pragma unroll
            for (int g = 0; g < SG; ++g) {
                int s = s0 + g;
                if (s < ns) {
                    unsigned ci = ci_lds[list_s[cur][s]];
                    beg[g] = ci >> 10; len[g] = (int)(ci & 1023u);
                } else { beg[g] = 0u; len[g] = 0; }
            }
            unsigned e[SG][3];
#pragma unroll
            for (int g = 0; g < SG; ++g) {
                int lm1 = (len[g] > 0) ? (len[g] - 1) : 0;
                int o0 = lane;       if (o0 > lm1) o0 = lm1;
                int o1 = 64 + lane;  if (o1 > lm1) o1 = lm1;
                int o2 = 128 + lane; if (o2 > lm1) o2 = lm1;
                e[g][0] = nzd[beg[g] + o0];   // clamped, always in-bounds
                e[g][1] = nzd[beg[g] + o1];
                e[g][2] = nzd[beg[g] + o2];
            }
#pragma unroll
            for (int g = 0; g < SG; ++g) {
#pragma unroll
                for (int k = 0; k < 3; ++k) {
                    if (k * 64 + lane < len[g]) {
                        unsigned ev = e[g][k];
                        atomicAdd(&I_acc[cur][ev & 0xFFFFu],
                                  __half2float(__ushort_as_half((unsigned short)(ev >> 16))));
                    }
                }
            }
            // safety tail (len > 192 — statistically absent)
#pragma unroll
            for (int g = 0; g < SG; ++g) {
                for (int p = 192 + lane; p < len[g]; p += 64) {
                    unsigned ev = nzd[beg[g] + p];
                    atomicAdd(&I_acc[cur][ev & 0xFFFFu],
                              __half2float(__ushort_as_half((unsigned short)(ev >> 16))));
                }
            }
        }
        __syncthreads();

        // ---- phase B: LIF update + aggregated spike append + next-input commit ----
#pragma unroll
        for (int it = 0; it < 3; ++it) {
            int n = tid + it * 1024;
            if (n >= N_TOT) break;              // whole waves drop out together
            float I = I_acc[cur][n];
            bool z;
            if (n < N_E) {
                float v = v_e[n], i = i_e[n];
                float vd = v + 0.05f * ((0.0f - v) + i);
                z = vd > 1.0f;
                v_e[n] = z ? 0.0f : vd;
                i_e[n] = 0.8f * i + I;
                if (z) cnt[n]++;
            } else {
                int m = n - N_E;
                float v = v_i[m], i = i_i[m];
                float vd = v + 0.1f * ((0.0f - v) + i);
                z = vd > 1.0f;
                v_i[m] = z ? 0.0f : vd;
                i_i[m] = 0.8f * i + I;
            }
            unsigned long long msk = __ballot(z);
            int wc = __popcll(msk);
            if (wc) {
                int base = 0;
                if (lane == 0) base = atomicAdd(&nspk_s[nxt], wc);
                base = __shfl(base, 0);
                if (z) list_s[nxt][base + __popcll(msk & ((1ull << lane) - 1ull))] = n;
            }
            if (tl + 1 < tc) {
                if (i_inp) {
                    I_acc[nxt][n] = (it == 0) ? pf0 : (it == 1) ? pf1 : pf2;
                } else {
                    I_acc[nxt][n] = inline_proj(x, We_in, Wi_in, b, t0 + tl + 1, n);
                }
            }
        }
        __syncthreads();
    }

    // ---- persist state ----
    int fin = tc & 1;
    for (int n = tid; n < N_E; n += 1024) {
        gv_e[(size_t)b * N_E + n] = v_e[n];
        gi_e[(size_t)b * N_E + n] = i_e[n];
        g_cnt[(size_t)b * N_E + n] = cnt[n];
    }
    for (int n = tid; n < N_I; n += 1024) {
        gv_i[(size_t)b * N_I + n] = v_i[n];
        gi_i[(size_t)b * N_I + n] = i_i[n];
    }
    if (tid == 0) g_nspk[b] = nspk_s[fin];
    for (int s = tid; s < nspk_s[fin]; s += 1024) g_list[(size_t)b * N_TOT + s] = list_s[fin][s];
}

// ------------------------------------------------------------------
// Readout: out[b, o] = (1/512) * sum_n cnt[b,n] * rw[o,n] + rb[o]
// ------------------------------------------------------------------
__global__ __launch_bounds__(256) void readout_kernel(
    const unsigned* __restrict__ g_cnt,
    const float* __restrict__ rw, const float* __restrict__ rb, float* __restrict__ out)
{
    int b = blockIdx.x, tid = threadIdx.x;
    float a0 = 0.f, a1 = 0.f, a2 = 0.f;
    for (int n = tid; n < N_E; n += 256) {
        float c = (float)g_cnt[(size_t)b * N_E + n];
        a0 = fmaf(c, rw[n], a0);
        a1 = fmaf(c, rw[N_E + n], a1);
        a2 = fmaf(c, rw[2 * N_E + n], a2);
    }
#pragma unroll
    for (int off = 32; off > 0; off >>= 1) {
        a0 += __shfl_down(a0, off);
        a1 += __shfl_down(a1, off);
        a2 += __shfl_down(a2, off);
    }
    __shared__ float part[3][4];
    int wid = tid >> 6, lane = tid & 63;
    if (lane == 0) { part[0][wid] = a0; part[1][wid] = a1; part[2][wid] = a2; }
    __syncthreads();
    if (tid == 0) {
        float s0 = part[0][0] + part[0][1] + part[0][2] + part[0][3];
        float s1 = part[1][0] + part[1][1] + part[1][2] + part[1][3];
        float s2 = part[2][0] + part[2][1] + part[2][2] + part[2][3];
        const float inv = 1.0f / 512.0f;
        out[b * 3 + 0] = fmaf(s0, inv, rb[0]);
        out[b * 3 + 1] = fmaf(s1, inv, rb[1]);
        out[b * 3 + 2] = fmaf(s2, inv, rb[2]);
    }
}

// ------------------------------------------------------------------
extern "C" void kernel_launch(void* const* d_in, const int* in_sizes, int n_in,
                              void* d_out, int out_size, void* d_ws, size_t ws_size,
                              hipStream_t stream)
{
    const float* x     = (const float*)d_in[0];
    const float* Wee   = (const float*)d_in[1];
    const float* Wie   = (const float*)d_in[2];
    const float* Wei   = (const float*)d_in[3];
    const float* Wii   = (const float*)d_in[4];
    const float* We_in = (const float*)d_in[5];
    const float* Wi_in = (const float*)d_in[6];
    const float* rw    = (const float*)d_in[7];
    const float* rb    = (const float*)d_in[8];
    float* out = (float*)d_out;
    char* ws = (char*)d_ws;

    size_t off = 0;
    auto alloc = [&](size_t bytes) {
        size_t o = off;
        off = (off + bytes + 255) & ~(size_t)255;
        return o;
    };
    size_t o_cnt     = alloc((size_t)N_TOT * 4);
    size_t o_colinfo = alloc((size_t)N_TOT * 4);
    size_t o_cursor  = alloc((size_t)N_TOT * 4);
    size_t o_nzd     = alloc((size_t)CAP * 4);   // packed u32 synapses
    size_t o_ve      = alloc((size_t)BATCH * N_E * 4);
    size_t o_ie      = alloc((size_t)BATCH * N_E * 4);
    size_t o_vi      = alloc((size_t)BATCH * N_I * 4);
    size_t o_ii      = alloc((size_t)BATCH * N_I * 4);
    size_t o_gcnt    = alloc((size_t)BATCH * N_E * 4);
    size_t o_glist   = alloc((size_t)BATCH * N_TOT * 4);
    size_t o_gnspk   = alloc((size_t)BATCH * 4);
    size_t o_iinp    = off;   // remainder for the input-projection chunk

    int tc = 0;
    if (ws_size > o_iinp) {
        size_t avail = ws_size - o_iinp;
        tc = TSTEPS;
        while (tc >= 2 && (size_t)tc * BATCH * N_TOT * 4 > avail) tc >>= 1;
        if (tc < 2) tc = 0;
    }

    unsigned* p_cnt     = (unsigned*)(ws + o_cnt);
    unsigned* p_colinfo = (unsigned*)(ws + o_colinfo);
    unsigned* p_cursor  = (unsigned*)(ws + o_cursor);
    unsigned* p_nzd     = (unsigned*)(ws + o_nzd);
    float*    p_ve      = (float*)(ws + o_ve);
    float*    p_ie      = (float*)(ws + o_ie);
    float*    p_vi      = (float*)(ws + o_vi);
    float*    p_ii      = (float*)(ws + o_ii);
    unsigned* p_gcnt    = (unsigned*)(ws + o_gcnt);
    int*      p_glist   = (int*)(ws + o_glist);
    int*      p_gnspk   = (int*)(ws + o_gnspk);
    float*    p_iinp    = (float*)(ws + o_iinp);

    // ---- build CSC of relu'd sparse weights ----
    hipMemsetAsync(ws + o_cnt, 0, (size_t)N_TOT * 4, stream);
    const long total = (long)N_E * N_E + (long)N_I * N_E + (long)N_E * N_I + (long)N_I * N_I;
    int nblk = (int)((total + 255) / 256);
    count_kernel<<<nblk, 256, 0, stream>>>(Wee, Wie, Wei, Wii, p_cnt);
    scan_kernel<<<1, 256, 0, stream>>>(p_cnt, p_colinfo, p_cursor);
    fill_kernel<<<nblk, 256, 0, stream>>>(Wee, Wie, Wei, Wii, p_cursor, p_nzd);

    // ---- time loop: proj GEMM chunk + persistent sim ----
    if (tc >= 2) {
        for (int t0 = 0; t0 < TSTEPS; t0 += tc) {
            dim3 pg(N_TOT / PBN, (tc * BATCH) / PBM);
            proj_kernel<<<pg, 256, 0, stream>>>(x, We_in, Wi_in, p_iinp, t0);
            sim_kernel<<<BATCH, 1024, 0, stream>>>(
                p_iinp, x, We_in, Wi_in, p_colinfo, p_nzd,
                p_ve, p_ie, p_vi, p_ii, p_gcnt, p_glist, p_gnspk,
                t0, tc, (t0 == 0) ? 1 : 0);
        }
    } else {
        sim_kernel<<<BATCH, 1024, 0, stream>>>(
            nullptr, x, We_in, Wi_in, p_colinfo, p_nzd,
            p_ve, p_ie, p_vi, p_ii, p_gcnt, p_glist, p_gnspk,
            0, TSTEPS, 1);
    }

    // ---- readout ----
    readout_kernel<<<BATCH, 256, 0, stream>>>(p_gcnt, rw, rb, out);
}

// Round 8
// 3275.769 us; speedup vs baseline: 1.2745x; 1.1147x over previous
//
#include <hip/hip_runtime.h>
#include <hip/hip_fp16.h>
#include <cstdint>
#include <cstddef>

#define N_E 2048
#define N_I 512
#define N_TOT 2560
#define BATCH 64
#define TSTEPS 512
#define INDIM 128
#define CAP (1u << 20)   // nz capacity (expected ~330K)

// ------------------------------------------------------------------
// CSC build: counts -> scan -> fill.
//   col 0..2047   : E presynaptic j  (Wee -> post 0..2047 (+), Wie -> 2048+r (+))
//   col 2048..2559: I presynaptic j  (Wei -> post 0..2047 (-), Wii -> 2048+r (-))
// Synapse packed u32: (f16_bits(w) << 16) | post_index   (4 B/synapse)
// colinfo packed u32: (col_begin << 10) | col_len
// ------------------------------------------------------------------
__global__ void count_kernel(const float* __restrict__ Wee, const float* __restrict__ Wie,
                             const float* __restrict__ Wei, const float* __restrict__ Wii,
                             unsigned* __restrict__ cnt)
{
    const long EE = (long)N_E * N_E;
    const long IE = (long)N_I * N_E;
    const long EI = (long)N_E * N_I;
    const long II = (long)N_I * N_I;
    long idx = (long)blockIdx.x * 256 + threadIdx.x;
    long total = EE + IE + EI + II;
    if (idx >= total) return;
    float v; int col;
    if (idx < EE) {
        v = Wee[idx]; col = (int)(idx & (N_E - 1));
    } else if (idx < EE + IE) {
        long j = idx - EE; v = Wie[j]; col = (int)(j & (N_E - 1));
    } else if (idx < EE + IE + EI) {
        long j = idx - EE - IE; v = Wei[j]; col = N_E + (int)(j & (N_I - 1));
    } else {
        long j = idx - EE - IE - EI; v = Wii[j]; col = N_E + (int)(j & (N_I - 1));
    }
    if (v > 0.0f) atomicAdd(&cnt[col], 1u);
}

__global__ void scan_kernel(const unsigned* __restrict__ cnt,
                            unsigned* __restrict__ colinfo, unsigned* __restrict__ cursor)
{
    __shared__ unsigned sums[256];
    int t = threadIdx.x;
    int base = t * 10;                 // 2560 = 256 * 10
    unsigned loc[10];
    unsigned s = 0;
    for (int i = 0; i < 10; ++i) { loc[i] = s; s += cnt[base + i]; }
    sums[t] = s;
    __syncthreads();
    if (t == 0) {
        unsigned a = 0;
        for (int i = 0; i < 256; ++i) { unsigned v = sums[i]; sums[i] = a; a += v; }
    }
    __syncthreads();
    unsigned offt = sums[t];
    for (int i = 0; i < 10; ++i) {
        unsigned beg = offt + loc[i];
        if (beg > CAP) beg = CAP;
        unsigned len = cnt[base + i];
        if (len > 1023u) len = 1023u;
        colinfo[base + i] = (beg << 10) | len;
        cursor[base + i] = beg;
    }
}

__global__ void fill_kernel(const float* __restrict__ Wee, const float* __restrict__ Wie,
                            const float* __restrict__ Wei, const float* __restrict__ Wii,
                            unsigned* __restrict__ cursor,
                            unsigned* __restrict__ nzd)
{
    const long EE = (long)N_E * N_E;
    const long IE = (long)N_I * N_E;
    const long EI = (long)N_E * N_I;
    const long II = (long)N_I * N_I;
    long idx = (long)blockIdx.x * 256 + threadIdx.x;
    long total = EE + IE + EI + II;
    if (idx >= total) return;
    float v; int col; int post; bool neg;
    if (idx < EE) {
        int r = (int)(idx >> 11), c = (int)(idx & (N_E - 1));
        v = Wee[idx]; post = r; col = c; neg = false;
    } else if (idx < EE + IE) {
        long j = idx - EE;
        int r = (int)(j >> 11), c = (int)(j & (N_E - 1));
        v = Wie[j]; post = N_E + r; col = c; neg = false;
    } else if (idx < EE + IE + EI) {
        long j = idx - EE - IE;
        int r = (int)(j >> 9), c = (int)(j & (N_I - 1));
        v = Wei[j]; post = r; col = N_E + c; neg = true;
    } else {
        long j = idx - EE - IE - EI;
        int r = (int)(j >> 9), c = (int)(j & (N_I - 1));
        v = Wii[j]; post = N_E + r; col = N_E + c; neg = true;
    }
    if (v > 0.0f) {
        unsigned pos = atomicAdd(&cursor[col], 1u);
        if (pos < CAP) {
            float w = neg ? -v : v;
            unsigned short h = __half_as_ushort(__float2half(w));
            nzd[pos] = ((unsigned)h << 16) | (unsigned)post;
        }
    }
}

// ------------------------------------------------------------------
// Input projection GEMM: out[(tl*64+b)*2560 + n] = dot(x[b, t0+tl, :], W[n, :])
// ------------------------------------------------------------------
#define PBM 128
#define PBN 64
#define PBK 32
__global__ __launch_bounds__(256) void proj_kernel(
    const float* __restrict__ x, const float* __restrict__ We, const float* __restrict__ Wi,
    float* __restrict__ out, int t0)
{
    __shared__ __align__(16) float As[PBK][132];
    __shared__ __align__(16) float Bs[PBK][68];
    int tid = threadIdx.x;
    int bx = blockIdx.x, by = blockIdx.y;
    int tx = tid & 15, ty = tid >> 4;
    float acc[8][4];
#pragma unroll
    for (int i = 0; i < 8; ++i)
#pragma unroll
        for (int j = 0; j < 4; ++j) acc[i][j] = 0.0f;

    for (int kb = 0; kb < INDIM; kb += PBK) {
#pragma unroll
        for (int it = 0; it < 4; ++it) {
            int idx = it * 256 + tid;
            int kq = idx & 7, ml = idx >> 3;
            int m = by * PBM + ml;
            int b = m & 63, tl = m >> 6;
            const float* arow = x + ((size_t)b * TSTEPS + (size_t)(t0 + tl)) * INDIM;
            float4 v = *(const float4*)(arow + kb + kq * 4);
            As[kq * 4 + 0][ml] = v.x; As[kq * 4 + 1][ml] = v.y;
            As[kq * 4 + 2][ml] = v.z; As[kq * 4 + 3][ml] = v.w;
        }
#pragma unroll
        for (int it = 0; it < 2; ++it) {
            int idx = it * 256 + tid;
            int kq = idx & 7, nl = idx >> 3;
            int n = bx * PBN + nl;
            const float* brow = (n < N_E) ? (We + (size_t)n * INDIM)
                                          : (Wi + (size_t)(n - N_E) * INDIM);
            float4 v = *(const float4*)(brow + kb + kq * 4);
            Bs[kq * 4 + 0][nl] = v.x; Bs[kq * 4 + 1][nl] = v.y;
            Bs[kq * 4 + 2][nl] = v.z; Bs[kq * 4 + 3][nl] = v.w;
        }
        __syncthreads();
#pragma unroll
        for (int k = 0; k < PBK; ++k) {
            float4 a0 = *(const float4*)&As[k][ty * 8];
            float4 a1 = *(const float4*)&As[k][ty * 8 + 4];
            float4 b0 = *(const float4*)&Bs[k][tx * 4];
            float a[8] = {a0.x, a0.y, a0.z, a0.w, a1.x, a1.y, a1.z, a1.w};
            float bb[4] = {b0.x, b0.y, b0.z, b0.w};
#pragma unroll
            for (int i = 0; i < 8; ++i)
#pragma unroll
                for (int j = 0; j < 4; ++j)
                    acc[i][j] = fmaf(a[i], bb[j], acc[i][j]);
        }
        __syncthreads();
    }
#pragma unroll
    for (int i = 0; i < 8; ++i) {
        int m = by * PBM + ty * 8 + i;
        float4 o = make_float4(acc[i][0], acc[i][1], acc[i][2], acc[i][3]);
        *(float4*)(out + (size_t)m * N_TOT + bx * PBN + tx * 4) = o;
    }
}

// ------------------------------------------------------------------
// on-the-fly input projection (fallback path only)
// ------------------------------------------------------------------
__device__ __forceinline__ float inline_proj(const float* __restrict__ x,
                                             const float* __restrict__ We_in,
                                             const float* __restrict__ Wi_in,
                                             int b, int t, int n)
{
    const float* xr = x + ((size_t)b * TSTEPS + (size_t)t) * INDIM;
    const float* wr = (n < N_E) ? (We_in + (size_t)n * INDIM)
                                : (Wi_in + (size_t)(n - N_E) * INDIM);
    float a = 0.f;
#pragma unroll
    for (int k = 0; k < INDIM; k += 4) {
        float4 w = *(const float4*)(wr + k);
        float4 xv = *(const float4*)(xr + k);
        a = fmaf(w.x, xv.x, a);
        a = fmaf(w.y, xv.y, a);
        a = fmaf(w.z, xv.z, a);
        a = fmaf(w.w, xv.w, a);
    }
    return a;
}

// ------------------------------------------------------------------
// Persistent per-batch LIF sim, DS-minimized:
//  - LIF state (v,i,cnt) in registers (3 posts/thread: tid, +1024, +2048)
//  - spike descriptors fetched lane-parallel, broadcast via shfl (VALU)
//  - input commit vectorized (float4) and overlapped with the atomic stream
//  - only remaining bulk DS work: the irreducible scatter atomics
// ------------------------------------------------------------------
__global__ __launch_bounds__(1024) void sim_kernel(
    const float* __restrict__ i_inp,   // precomputed input currents; may be null
    const float* __restrict__ x, const float* __restrict__ We_in, const float* __restrict__ Wi_in,
    const unsigned* __restrict__ colinfo, const unsigned* __restrict__ nzd,
    float* __restrict__ gv_e, float* __restrict__ gi_e,
    float* __restrict__ gv_i, float* __restrict__ gi_i,
    unsigned* __restrict__ g_cnt, int* __restrict__ g_list, int* __restrict__ g_nspk,
    int t0, int tc, int first)
{
    __shared__ float I_acc[2][N_TOT];
    __shared__ unsigned ci_lds[N_TOT];
    __shared__ int list_s[2][N_TOT];
    __shared__ int nspk_s[2];

    int b = blockIdx.x, tid = threadIdx.x;
    int lane = tid & 63, wid = tid >> 6;

    for (int n = tid; n < N_TOT; n += 1024) ci_lds[n] = colinfo[n];

    // register-resident LIF state
    float v0, v1, v2, c0, c1, c2;
    unsigned cnt0, cnt1;
    if (first) {
        v0 = v1 = v2 = 0.f; c0 = c1 = c2 = 0.f; cnt0 = cnt1 = 0u;
        if (tid == 0) nspk_s[0] = 0;
    } else {
        v0 = gv_e[(size_t)b * N_E + tid];
        c0 = gi_e[(size_t)b * N_E + tid];
        cnt0 = g_cnt[(size_t)b * N_E + tid];
        v1 = gv_e[(size_t)b * N_E + tid + 1024];
        c1 = gi_e[(size_t)b * N_E + tid + 1024];
        cnt1 = g_cnt[(size_t)b * N_E + tid + 1024];
        if (tid < N_I) { v2 = gv_i[(size_t)b * N_I + tid]; c2 = gi_i[(size_t)b * N_I + tid]; }
        else { v2 = 0.f; c2 = 0.f; }
        if (tid == 0) nspk_s[0] = g_nspk[b];
        __syncthreads();
        for (int s = tid; s < nspk_s[0]; s += 1024) list_s[0][s] = g_list[(size_t)b * N_TOT + s];
    }
    // initial input commit into I_acc[0] (local row 0 of this chunk)
    if (i_inp) {
        if (tid < 640) {
            float4 vv = *(const float4*)(i_inp + (size_t)b * N_TOT + tid * 4);
            *(float4*)&I_acc[0][tid * 4] = vv;
        }
    } else {
        for (int n = tid; n < N_TOT; n += 1024)
            I_acc[0][n] = inline_proj(x, We_in, Wi_in, b, t0, n);
    }
    __syncthreads();

    for (int tl = 0; tl < tc; ++tl) {
        int cur = tl & 1, nxt = cur ^ 1;
        if (tid == 0) nspk_s[nxt] = 0;

        // ---- phase A: commit next input into I_acc[nxt] (overlaps atomics);
        //      scatter this step's spikes into I_acc[cur] ----
        if (tl + 1 < tc) {
            if (i_inp) {
                if (tid < 640) {
                    float4 vv = *(const float4*)(i_inp +
                        ((size_t)(tl + 1) * BATCH + b) * N_TOT + tid * 4);
                    *(float4*)&I_acc[nxt][tid * 4] = vv;
                }
            } else {
                for (int n = tid; n < N_TOT; n += 1024)
                    I_acc[nxt][n] = inline_proj(x, We_in, Wi_in, b, t0 + tl + 1, n);
            }
        }

        int ns = nspk_s[cur];
        int Mw = (ns > wid) ? ((ns - wid + 15) >> 4) : 0;   // spikes for this wave
        for (int m0 = 0; m0 < Mw; m0 += 64) {
            int m = m0 + lane;
            unsigned ci = 0u;
            if (m < Mw) ci = ci_lds[list_s[cur][wid + (m << 4)]];  // 2 DS reads / 64 spikes
            int nv = Mw - m0; if (nv > 64) nv = 64;
            for (int k = 0; k < nv; ++k) {
                unsigned cik = (unsigned)__shfl((int)ci, k);       // VALU broadcast
                int len = (int)(cik & 1023u);
                unsigned beg = cik >> 10;
                unsigned e0 = (lane < len) ? nzd[beg + lane] : 0u;
                unsigned e1 = (lane + 64 < len) ? nzd[beg + lane + 64] : 0u;
                unsigned e2 = (lane + 128 < len) ? nzd[beg + lane + 128] : 0u;
                if (lane < len)
                    atomicAdd(&I_acc[cur][e0 & 0xFFFFu],
                              __half2float(__ushort_as_half((unsigned short)(e0 >> 16))));
                if (lane + 64 < len)
                    atomicAdd(&I_acc[cur][e1 & 0xFFFFu],
                              __half2float(__ushort_as_half((unsigned short)(e1 >> 16))));
                if (lane + 128 < len)
                    atomicAdd(&I_acc[cur][e2 & 0xFFFFu],
                              __half2float(__ushort_as_half((unsigned short)(e2 >> 16))));
                for (int p = lane + 192; p < len; p += 64) {      // statistically absent
                    unsigned ev = nzd[beg + p];
                    atomicAdd(&I_acc[cur][ev & 0xFFFFu],
                              __half2float(__ushort_as_half((unsigned short)(ev >> 16))));
                }
            }
        }
        __syncthreads();

        // ---- phase B: register LIF + single-atomic aggregated spike append ----
        {
            float I0 = I_acc[cur][tid];
            float I1 = I_acc[cur][tid + 1024];
            float I2 = (tid < N_I) ? I_acc[cur][tid + 2048] : 0.f;

            float vd0 = v0 + 0.05f * (c0 - v0);
            bool z0 = vd0 > 1.0f;
            v0 = z0 ? 0.f : vd0;  c0 = 0.8f * c0 + I0;  if (z0) cnt0++;

            float vd1 = v1 + 0.05f * (c1 - v1);
            bool z1 = vd1 > 1.0f;
            v1 = z1 ? 0.f : vd1;  c1 = 0.8f * c1 + I1;  if (z1) cnt1++;

            float vd2 = v2 + 0.1f * (c2 - v2);
            bool z2 = (tid < N_I) && (vd2 > 1.0f);
            v2 = z2 ? 0.f : vd2;  c2 = 0.8f * c2 + I2;

            unsigned long long mk0 = __ballot(z0);
            unsigned long long mk1 = __ballot(z1);
            unsigned long long mk2 = __ballot(z2);
            int wc0 = __popcll(mk0), wc1 = __popcll(mk1), wc2 = __popcll(mk2);
            int tot = wc0 + wc1 + wc2;
            if (tot) {
                int base = 0;
                if (lane == 0) base = atomicAdd(&nspk_s[nxt], tot);
                base = __shfl(base, 0);
                unsigned long long below = (lane == 63) ? ~0ull : ((1ull << (lane + 1)) - 1ull);
                unsigned long long pre = (1ull << lane) - 1ull;
                if (z0) list_s[nxt][base + __popcll(mk0 & pre)] = tid;
                if (z1) list_s[nxt][base + wc0 + __popcll(mk1 & pre)] = tid + 1024;
                if (z2) list_s[nxt][base + wc0 + wc1 + __popcll(mk2 & pre)] = tid + 2048;
                (void)below;
            }
        }
        __syncthreads();
    }

    // ---- persist state ----
    gv_e[(size_t)b * N_E + tid] = v0;
    gi_e[(size_t)b * N_E + tid] = c0;
    g_cnt[(size_t)b * N_E + tid] = cnt0;
    gv_e[(size_t)b * N_E + tid + 1024] = v1;
    gi_e[(size_t)b * N_E + tid + 1024] = c1;
    g_cnt[(size_t)b * N_E + tid + 1024] = cnt1;
    if (tid < N_I) {
        gv_i[(size_t)b * N_I + tid] = v2;
        gi_i[(size_t)b * N_I + tid] = c2;
    }
    int fin = tc & 1;
    if (tid == 0) g_nspk[b] = nspk_s[fin];
    for (int s = tid; s < nspk_s[fin]; s += 1024) g_list[(size_t)b * N_TOT + s] = list_s[fin][s];
}

// ------------------------------------------------------------------
// Readout: out[b, o] = (1/512) * sum_n cnt[b,n] * rw[o,n] + rb[o]
// ------------------------------------------------------------------
__global__ __launch_bounds__(256) void readout_kernel(
    const unsigned* __restrict__ g_cnt,
    const float* __restrict__ rw, const float* __restrict__ rb, float* __restrict__ out)
{
    int b = blockIdx.x, tid = threadIdx.x;
    float a0 = 0.f, a1 = 0.f, a2 = 0.f;
    for (int n = tid; n < N_E; n += 256) {
        float c = (float)g_cnt[(size_t)b * N_E + n];
        a0 = fmaf(c, rw[n], a0);
        a1 = fmaf(c, rw[N_E + n], a1);
        a2 = fmaf(c, rw[2 * N_E + n], a2);
    }
#pragma unroll
    for (int off = 32; off > 0; off >>= 1) {
        a0 += __shfl_down(a0, off);
        a1 += __shfl_down(a1, off);
        a2 += __shfl_down(a2, off);
    }
    __shared__ float part[3][4];
    int wid = tid >> 6, lane = tid & 63;
    if (lane == 0) { part[0][wid] = a0; part[1][wid] = a1; part[2][wid] = a2; }
    __syncthreads();
    if (tid == 0) {
        float s0 = part[0][0] + part[0][1] + part[0][2] + part[0][3];
        float s1 = part[1][0] + part[1][1] + part[1][2] + part[1][3];
        float s2 = part[2][0] + part[2][1] + part[2][2] + part[2][3];
        const float inv = 1.0f / 512.0f;
        out[b * 3 + 0] = fmaf(s0, inv, rb[0]);
        out[b * 3 + 1] = fmaf(s1, inv, rb[1]);
        out[b * 3 + 2] = fmaf(s2, inv, rb[2]);
    }
}

// ------------------------------------------------------------------
extern "C" void kernel_launch(void* const* d_in, const int* in_sizes, int n_in,
                              void* d_out, int out_size, void* d_ws, size_t ws_size,
                              hipStream_t stream)
{
    const float* x     = (const float*)d_in[0];
    const float* Wee   = (const float*)d_in[1];
    const float* Wie   = (const float*)d_in[2];
    const float* Wei   = (const float*)d_in[3];
    const float* Wii   = (const float*)d_in[4];
    const float* We_in = (const float*)d_in[5];
    const float* Wi_in = (const float*)d_in[6];
    const float* rw    = (const float*)d_in[7];
    const float* rb    = (const float*)d_in[8];
    float* out = (float*)d_out;
    char* ws = (char*)d_ws;

    size_t off = 0;
    auto alloc = [&](size_t bytes) {
        size_t o = off;
        off = (off + bytes + 255) & ~(size_t)255;
        return o;
    };
    size_t o_cnt     = alloc((size_t)N_TOT * 4);
    size_t o_colinfo = alloc((size_t)N_TOT * 4);
    size_t o_cursor  = alloc((size_t)N_TOT * 4);
    size_t o_nzd     = alloc((size_t)CAP * 4);   // packed u32 synapses
    size_t o_ve      = alloc((size_t)BATCH * N_E * 4);
    size_t o_ie      = alloc((size_t)BATCH * N_E * 4);
    size_t o_vi      = alloc((size_t)BATCH * N_I * 4);
    size_t o_ii      = alloc((size_t)BATCH * N_I * 4);
    size_t o_gcnt    = alloc((size_t)BATCH * N_E * 4);
    size_t o_glist   = alloc((size_t)BATCH * N_TOT * 4);
    size_t o_gnspk   = alloc((size_t)BATCH * 4);
    size_t o_iinp    = off;   // remainder for the input-projection chunk

    int tc = 0;
    if (ws_size > o_iinp) {
        size_t avail = ws_size - o_iinp;
        tc = TSTEPS;
        while (tc >= 2 && (size_t)tc * BATCH * N_TOT * 4 > avail) tc >>= 1;
        if (tc < 2) tc = 0;
    }

    unsigned* p_cnt     = (unsigned*)(ws + o_cnt);
    unsigned* p_colinfo = (unsigned*)(ws + o_colinfo);
    unsigned* p_cursor  = (unsigned*)(ws + o_cursor);
    unsigned* p_nzd     = (unsigned*)(ws + o_nzd);
    float*    p_ve      = (float*)(ws + o_ve);
    float*    p_ie      = (float*)(ws + o_ie);
    float*    p_vi      = (float*)(ws + o_vi);
    float*    p_ii      = (float*)(ws + o_ii);
    unsigned* p_gcnt    = (unsigned*)(ws + o_gcnt);
    int*      p_glist   = (int*)(ws + o_glist);
    int*      p_gnspk   = (int*)(ws + o_gnspk);
    float*    p_iinp    = (float*)(ws + o_iinp);

    // ---- build CSC of relu'd sparse weights ----
    hipMemsetAsync(ws + o_cnt, 0, (size_t)N_TOT * 4, stream);
    const long total = (long)N_E * N_E + (long)N_I * N_E + (long)N_E * N_I + (long)N_I * N_I;
    int nblk = (int)((total + 255) / 256);
    count_kernel<<<nblk, 256, 0, stream>>>(Wee, Wie, Wei, Wii, p_cnt);
    scan_kernel<<<1, 256, 0, stream>>>(p_cnt, p_colinfo, p_cursor);
    fill_kernel<<<nblk, 256, 0, stream>>>(Wee, Wie, Wei, Wii, p_cursor, p_nzd);

    // ---- time loop: proj GEMM chunk + persistent sim ----
    if (tc >= 2) {
        for (int t0 = 0; t0 < TSTEPS; t0 += tc) {
            dim3 pg(N_TOT / PBN, (tc * BATCH) / PBM);
            proj_kernel<<<pg, 256, 0, stream>>>(x, We_in, Wi_in, p_iinp, t0);
            sim_kernel<<<BATCH, 1024, 0, stream>>>(
                p_iinp, x, We_in, Wi_in, p_colinfo, p_nzd,
                p_ve, p_ie, p_vi, p_ii, p_gcnt, p_glist, p_gnspk,
                t0, tc, (t0 == 0) ? 1 : 0);
        }
    } else {
        sim_kernel<<<BATCH, 1024, 0, stream>>>(
            nullptr, x, We_in, Wi_in, p_colinfo, p_nzd,
            p_ve, p_ie, p_vi, p_ii, p_gcnt, p_glist, p_gnspk,
            0, TSTEPS, 1);
    }

    // ---- readout ----
    readout_kernel<<<BATCH, 256, 0, stream>>>(p_gcnt, rw, rb, out);
}